// Round 4
// baseline (736.612 us; speedup 1.0000x reference)
//
#include <hip/hip_runtime.h>

// RGCN 2-layer forward, f32, CSR counting-sort + fully fused layer-1 GEMM.
// L1: one kernel: per block of 64 nodes, gather-mean x[src] per (node,rel) K-chunk
//     directly into LDS (block's edges are a contiguous slice of sorted_src),
//     then 64x128 f32 GEMM with K=1152 = [8 rel x 128 | root 128]. No agg1 buffer.
// L2: t[n,0:18] = h[n] @ [W2_r0..W2_r7 | Wr2]  (transform first; mean commutes),
//     out[n] = sum_r mean_{e in seg(n,r)} t[src_e, 2r:2r+2] + t[n,16:18] + b2.

#define NR 8
#define DH 128
#define CAP 2048  // per-block edge-index LDS cache (mean 1024, ~30 sigma headroom + global fallback)

// ---------- counting sort ----------
__global__ __launch_bounds__(256) void k_hist(const int* __restrict__ dst, const int* __restrict__ et,
                                              int* __restrict__ hist, int E) {
  int e = blockIdx.x * 256 + threadIdx.x;
  if (e < E) atomicAdd(&hist[dst[e] * NR + et[e]], 1);
}

__global__ __launch_bounds__(256) void k_scan_local(const int* __restrict__ hist, int* __restrict__ offs,
                                                    int* __restrict__ blksum, int S) {
  __shared__ int tsum[256];
  int tid = threadIdx.x;
  int base = blockIdx.x * 1024 + tid * 4;
  int v[4], tot = 0;
  #pragma unroll
  for (int i = 0; i < 4; i++) { v[i] = (base + i < S) ? hist[base + i] : 0; tot += v[i]; }
  tsum[tid] = tot;
  __syncthreads();
  for (int off = 1; off < 256; off <<= 1) {
    int val = tsum[tid];
    int add = (tid >= off) ? tsum[tid - off] : 0;
    __syncthreads();
    tsum[tid] = val + add;
    __syncthreads();
  }
  int run = tsum[tid] - tot;
  #pragma unroll
  for (int i = 0; i < 4; i++) {
    if (base + i < S) offs[base + i] = run;
    run += v[i];
  }
  if (tid == 255) blksum[blockIdx.x] = tsum[255];
}

__global__ __launch_bounds__(512) void k_scan_blk(const int* __restrict__ blksum, int* __restrict__ blkoff, int NB) {
  __shared__ int s[512];
  int tid = threadIdx.x;
  int v = (tid < NB) ? blksum[tid] : 0;
  s[tid] = v;
  __syncthreads();
  for (int off = 1; off < 512; off <<= 1) {
    int val = s[tid];
    int add = (tid >= off) ? s[tid - off] : 0;
    __syncthreads();
    s[tid] = val + add;
    __syncthreads();
  }
  if (tid < NB) blkoff[tid] = s[tid] - v;
}

__global__ __launch_bounds__(256) void k_scan_add(int* __restrict__ offs, const int* __restrict__ blkoff, int S) {
  int tid = threadIdx.x;
  int base = blockIdx.x * 1024 + tid * 4;
  int add = blkoff[blockIdx.x];
  #pragma unroll
  for (int i = 0; i < 4; i++)
    if (base + i < S) offs[base + i] += add;
}

__global__ __launch_bounds__(256) void k_scatter_idx(const int* __restrict__ src, const int* __restrict__ dst,
                                                     const int* __restrict__ et, int* __restrict__ offs,
                                                     int* __restrict__ sorted_src, int E) {
  int e = blockIdx.x * 256 + threadIdx.x;
  if (e >= E) return;
  int seg = dst[e] * NR + et[e];
  int pos = atomicAdd(&offs[seg], 1);
  sorted_src[pos] = src[e];
}

// ---------- fused layer-1: gather-aggregate + GEMM ----------
// Block: 64 nodes, 128 threads (2 waves). Thread tile 8 rows x (4+4 split cols).
// At transposed [kk][row] (b128 broadcast reads), Bs [kk][col] (proven conflict-free).
__global__ __launch_bounds__(128) void k_l1_fused(const int* __restrict__ offs, const int* __restrict__ hist,
                                                  const int* __restrict__ sorted_src, const float* __restrict__ x,
                                                  const float* __restrict__ W1, const float* __restrict__ Wr1,
                                                  const float* __restrict__ b1, float* __restrict__ h,
                                                  int N, int E) {
  __shared__ float At[32 * 68];
  __shared__ float Bs[32 * 132];
  __shared__ int Eidx[CAP];
  __shared__ int st_l[512];
  __shared__ int cnt_l[512];
  __shared__ float inv_l[512];

  int tid = threadIdx.x;
  int n0 = blockIdx.x * 64;
  int seg0 = n0 * NR;
  int S = N * NR;

  // segment metadata for this block's 512 contiguous segments
  #pragma unroll
  for (int p = 0; p < 4; p++) {
    int sid = p * 128 + tid;
    int seg = seg0 + sid;
    int en = 0, cc = 0;
    if (seg < S) { en = offs[seg]; cc = hist[seg]; }
    st_l[sid] = en - cc;
    cnt_l[sid] = cc;
    inv_l[sid] = 1.f / fmaxf((float)cc, 1.f);
  }
  __syncthreads();
  int e_lo = st_l[0];  // block's edges = contiguous slice [e_lo, ...)
  #pragma unroll
  for (int p = 0; p < CAP / 128; p++) {
    int i = p * 128 + tid;
    int g = e_lo + i;
    Eidx[i] = (g < E) ? sorted_src[g] : 0;
  }
  __syncthreads();

  float acc[8][8];
  #pragma unroll
  for (int i = 0; i < 8; i++)
    #pragma unroll
    for (int j = 0; j < 8; j++) acc[i][j] = 0.f;

  int r0 = (tid >> 4) * 8;   // 8 output rows
  int c0 = (tid & 15) * 4;   // cols c0..c0+3 and c0+64..c0+67
  int grow = tid >> 1;       // gather: 2 threads per row
  int gt = tid & 1;          // each covers 16 of the 32 k-dims

  int bk = tid >> 5, bc = (tid & 31) * 4;  // B staging coords
  float4 rb[8];
  #pragma unroll
  for (int i = 0; i < 8; i++)  // prefetch kc=0 (W1)
    rb[i] = *(const float4*)(W1 + (size_t)(bk + 4 * i) * 128 + bc);

  for (int kc = 0; kc < 36; kc++) {
    // Bs <- prefetched regs
    #pragma unroll
    for (int i = 0; i < 8; i++)
      *(float4*)(Bs + (bk + 4 * i) * 132 + bc) = rb[i];

    // stage A chunk (64 rows x 32 k)
    float4 a0 = make_float4(0.f, 0.f, 0.f, 0.f), a1 = a0, a2 = a0, a3 = a0;
    if (kc < 32) {
      int r = kc >> 2, d0 = (kc & 3) << 5;
      int sid = grow * NR + r;
      int stg = st_l[sid], cn = cnt_l[sid];
      for (int i = 0; i < cn; i++) {
        int g = stg + i;
        int loc = g - e_lo;
        int s = (loc < CAP) ? Eidx[loc] : sorted_src[g];
        const float4* xp = (const float4*)(x + (size_t)s * DH + d0 + gt * 16);
        float4 v0 = xp[0], v1 = xp[1], v2 = xp[2], v3 = xp[3];
        a0.x += v0.x; a0.y += v0.y; a0.z += v0.z; a0.w += v0.w;
        a1.x += v1.x; a1.y += v1.y; a1.z += v1.z; a1.w += v1.w;
        a2.x += v2.x; a2.y += v2.y; a2.z += v2.z; a2.w += v2.w;
        a3.x += v3.x; a3.y += v3.y; a3.z += v3.z; a3.w += v3.w;
      }
      float inv = inv_l[sid];
      a0.x *= inv; a0.y *= inv; a0.z *= inv; a0.w *= inv;
      a1.x *= inv; a1.y *= inv; a1.z *= inv; a1.w *= inv;
      a2.x *= inv; a2.y *= inv; a2.z *= inv; a2.w *= inv;
      a3.x *= inv; a3.y *= inv; a3.z *= inv; a3.w *= inv;
    } else {
      int d0 = (kc - 32) << 5;
      int n = n0 + grow;
      if (n < N) {
        const float4* xp = (const float4*)(x + (size_t)n * DH + d0 + gt * 16);
        a0 = xp[0]; a1 = xp[1]; a2 = xp[2]; a3 = xp[3];
      }
    }
    {
      float vals[16] = {a0.x, a0.y, a0.z, a0.w, a1.x, a1.y, a1.z, a1.w,
                        a2.x, a2.y, a2.z, a2.w, a3.x, a3.y, a3.z, a3.w};
      int kb = gt * 16;
      #pragma unroll
      for (int j = 0; j < 16; j++)
        At[(kb + j) * 68 + grow] = vals[j];
    }
    __syncthreads();

    if (kc < 35) {  // prefetch next B while computing
      int kn = kc + 1;
      const float* bbase = (kn < 32) ? (W1 + (size_t)kn * 32 * 128)
                                     : (Wr1 + (size_t)(kn - 32) * 32 * 128);
      #pragma unroll
      for (int i = 0; i < 8; i++)
        rb[i] = *(const float4*)(bbase + (size_t)(bk + 4 * i) * 128 + bc);
    }

    #pragma unroll
    for (int kk = 0; kk < 32; kk++) {
      float4 av0 = *(const float4*)(At + kk * 68 + r0);
      float4 av1 = *(const float4*)(At + kk * 68 + r0 + 4);
      float4 bv0 = *(const float4*)(Bs + kk * 132 + c0);
      float4 bv1 = *(const float4*)(Bs + kk * 132 + c0 + 64);
      float av[8] = {av0.x, av0.y, av0.z, av0.w, av1.x, av1.y, av1.z, av1.w};
      float bv[8] = {bv0.x, bv0.y, bv0.z, bv0.w, bv1.x, bv1.y, bv1.z, bv1.w};
      #pragma unroll
      for (int i = 0; i < 8; i++)
        #pragma unroll
        for (int j = 0; j < 8; j++) acc[i][j] += av[i] * bv[j];
    }
    __syncthreads();
  }

  #pragma unroll
  for (int i = 0; i < 8; i++) {
    int n = n0 + r0 + i;
    if (n < N) {
      float4 o0, o1;
      o0.x = fmaxf(acc[i][0] + b1[c0 + 0], 0.f);
      o0.y = fmaxf(acc[i][1] + b1[c0 + 1], 0.f);
      o0.z = fmaxf(acc[i][2] + b1[c0 + 2], 0.f);
      o0.w = fmaxf(acc[i][3] + b1[c0 + 3], 0.f);
      o1.x = fmaxf(acc[i][4] + b1[c0 + 64], 0.f);
      o1.y = fmaxf(acc[i][5] + b1[c0 + 65], 0.f);
      o1.z = fmaxf(acc[i][6] + b1[c0 + 66], 0.f);
      o1.w = fmaxf(acc[i][7] + b1[c0 + 67], 0.f);
      *(float4*)(h + (size_t)n * DH + c0) = o0;
      *(float4*)(h + (size_t)n * DH + c0 + 64) = o1;
    }
  }
}

// ---------- layer-2 transform: t[n,0:18] = h[n] @ [W2_r(:,0:2) ... | Wr2] ----------
__global__ __launch_bounds__(256) void k_l2trans(const float* __restrict__ h, const float* __restrict__ W2,
                                                 const float* __restrict__ Wr2, float* __restrict__ t, int N) {
  __shared__ float Wt[18 * 128];
  int tid = threadIdx.x;
  for (int i = tid; i < 2304; i += 256) {
    float v; int oc, d;
    if (i < 2048) { int r = i >> 8, rem = i & 255; d = rem >> 1; int c = rem & 1; oc = r * 2 + c; v = W2[i]; }
    else { int i2 = i - 2048; d = i2 >> 1; int c = i2 & 1; oc = 16 + c; v = Wr2[i2]; }
    Wt[oc * 128 + d] = v;
  }
  __syncthreads();
  int node = blockIdx.x * 4 + (tid >> 6);
  int lane = tid & 63;
  if (node >= N) return;
  float2 hv = *(const float2*)(h + (size_t)node * DH + lane * 2);
  #pragma unroll
  for (int oc = 0; oc < 18; oc++) {
    float2 w = *(const float2*)(Wt + oc * 128 + lane * 2);
    float p = hv.x * w.x + hv.y * w.y;
    p += __shfl_xor(p, 32); p += __shfl_xor(p, 16); p += __shfl_xor(p, 8);
    p += __shfl_xor(p, 4);  p += __shfl_xor(p, 2);  p += __shfl_xor(p, 1);
    if (lane == 0) t[(size_t)node * 18 + oc] = p;
  }
}

// ---------- output: gather tiny t values per segment ----------
__global__ __launch_bounds__(256) void k_out2(const int* __restrict__ offs, const int* __restrict__ hist,
                                              const int* __restrict__ sorted_src, const float* __restrict__ t,
                                              const float* __restrict__ b2, float* __restrict__ out, int N) {
  int n = blockIdx.x * 256 + threadIdx.x;
  if (n >= N) return;
  float o0 = t[(size_t)n * 18 + 16] + b2[0];
  float o1 = t[(size_t)n * 18 + 17] + b2[1];
  #pragma unroll
  for (int r = 0; r < NR; r++) {
    int seg = n * NR + r;
    int en = offs[seg], cc = hist[seg];
    float s0 = 0.f, s1 = 0.f;
    for (int i = en - cc; i < en; i++) {
      int s = sorted_src[i];
      s0 += t[(size_t)s * 18 + r * 2];
      s1 += t[(size_t)s * 18 + r * 2 + 1];
    }
    float inv = 1.f / fmaxf((float)cc, 1.f);
    o0 += s0 * inv;
    o1 += s1 * inv;
  }
  out[(size_t)n * 2 + 0] = o0;
  out[(size_t)n * 2 + 1] = o1;
}

extern "C" void kernel_launch(void* const* d_in, const int* in_sizes, int n_in,
                              void* d_out, int out_size, void* d_ws, size_t ws_size,
                              hipStream_t stream) {
  const float* x   = (const float*)d_in[0];
  const int*   ei  = (const int*)d_in[1];
  const int*   et  = (const int*)d_in[2];
  const float* W1  = (const float*)d_in[3];
  const float* Wr1 = (const float*)d_in[4];
  const float* b1  = (const float*)d_in[5];
  const float* W2  = (const float*)d_in[6];
  const float* Wr2 = (const float*)d_in[7];
  const float* b2  = (const float*)d_in[8];
  float* out = (float*)d_out;

  int E = in_sizes[1] / 2;
  int N = in_sizes[0] / DH;
  int S = N * NR;
  const int* src = ei;
  const int* dst = ei + E;

  int* hist       = (int*)d_ws;                  // S
  int* offs       = hist + S;                    // S
  int* blksum     = offs + S;                    // 1024
  int* blkoff     = blksum + 1024;               // 1024
  int* sorted_src = blkoff + 1024;               // E
  size_t int_elems = (size_t)S * 2 + 2048 + E;
  int_elems = (int_elems + 3) & ~(size_t)3;
  float* h = (float*)(hist + int_elems);         // N*128
  float* t = h + (size_t)N * DH;                 // N*18

  hipMemsetAsync(hist, 0, sizeof(int) * (size_t)S, stream);

  k_hist<<<(E + 255) / 256, 256, 0, stream>>>(dst, et, hist, E);

  int NB = (S + 1023) / 1024;
  k_scan_local<<<NB, 256, 0, stream>>>(hist, offs, blksum, S);
  k_scan_blk<<<1, 512, 0, stream>>>(blksum, blkoff, NB);
  k_scan_add<<<NB, 256, 0, stream>>>(offs, blkoff, S);

  k_scatter_idx<<<(E + 255) / 256, 256, 0, stream>>>(src, dst, et, offs, sorted_src, E);

  k_l1_fused<<<(N + 63) / 64, 128, 0, stream>>>(offs, hist, sorted_src, x, W1, Wr1, b1, h, N, E);

  k_l2trans<<<(N + 3) / 4, 256, 0, stream>>>(h, W2, Wr2, t, N);

  k_out2<<<(N + 255) / 256, 256, 0, stream>>>(offs, hist, sorted_src, t, b2, out, N);
}

// Round 5
// 581.294 us; speedup vs baseline: 1.2672x; 1.2672x over previous
//
#include <hip/hip_runtime.h>

// RGCN 2-layer forward, f32. Counting-sort CSR; split gather (TLP-hidden) + tuned GEMM.
// L1: agg1[seg,:] = mean x[src]; h = relu([agg1|x] @ [W_rel1;W_root1] + b1)
//     GEMM: 256 thr, BM=128 BN=128 BK=32, 8x8 tile, At[kk][row] transposed (all-b128, conflict-free).
// L2: t[n,0:18] = h[n] @ [W2_r(:,0:2).. | Wr2]; out = sum_r mean t[src,2r:2r+2] + t[n,16:18] + b2.

#define NR 8
#define DH 128

// ---------- counting sort ----------
__global__ __launch_bounds__(256) void k_hist(const int* __restrict__ dst, const int* __restrict__ et,
                                              int* __restrict__ hist, int E) {
  int e = blockIdx.x * 256 + threadIdx.x;
  if (e < E) atomicAdd(&hist[dst[e] * NR + et[e]], 1);
}

__global__ __launch_bounds__(256) void k_scan_local(const int* __restrict__ hist, int* __restrict__ offs,
                                                    int* __restrict__ blksum, int S) {
  __shared__ int tsum[256];
  int tid = threadIdx.x;
  int base = blockIdx.x * 1024 + tid * 4;
  int v[4], tot = 0;
  #pragma unroll
  for (int i = 0; i < 4; i++) { v[i] = (base + i < S) ? hist[base + i] : 0; tot += v[i]; }
  tsum[tid] = tot;
  __syncthreads();
  for (int off = 1; off < 256; off <<= 1) {
    int val = tsum[tid];
    int add = (tid >= off) ? tsum[tid - off] : 0;
    __syncthreads();
    tsum[tid] = val + add;
    __syncthreads();
  }
  int run = tsum[tid] - tot;
  #pragma unroll
  for (int i = 0; i < 4; i++) {
    if (base + i < S) offs[base + i] = run;
    run += v[i];
  }
  if (tid == 255) blksum[blockIdx.x] = tsum[255];
}

__global__ __launch_bounds__(512) void k_scan_blk(const int* __restrict__ blksum, int* __restrict__ blkoff, int NB) {
  __shared__ int s[512];
  int tid = threadIdx.x;
  int v = (tid < NB) ? blksum[tid] : 0;
  s[tid] = v;
  __syncthreads();
  for (int off = 1; off < 512; off <<= 1) {
    int val = s[tid];
    int add = (tid >= off) ? s[tid - off] : 0;
    __syncthreads();
    s[tid] = val + add;
    __syncthreads();
  }
  if (tid < NB) blkoff[tid] = s[tid] - v;
}

__global__ __launch_bounds__(256) void k_scan_add(int* __restrict__ offs, const int* __restrict__ blkoff, int S) {
  int tid = threadIdx.x;
  int base = blockIdx.x * 1024 + tid * 4;
  int add = blkoff[blockIdx.x];
  #pragma unroll
  for (int i = 0; i < 4; i++)
    if (base + i < S) offs[base + i] += add;
}

__global__ __launch_bounds__(256) void k_scatter_idx(const int* __restrict__ src, const int* __restrict__ dst,
                                                     const int* __restrict__ et, int* __restrict__ offs,
                                                     int* __restrict__ sorted_src, int E) {
  int e = blockIdx.x * 256 + threadIdx.x;
  if (e >= E) return;
  int seg = dst[e] * NR + et[e];
  int pos = atomicAdd(&offs[seg], 1);
  sorted_src[pos] = src[e];
}

// ---------- layer 1 aggregate: one wave per segment, 4-deep pipelined gather ----------
__global__ __launch_bounds__(256) void k_agg1(const int* __restrict__ offs, const int* __restrict__ hist,
                                              const int* __restrict__ sorted_src, const float* __restrict__ x,
                                              float* __restrict__ agg1, int S) {
  int tid = threadIdx.x;
  int seg = blockIdx.x * 4 + (tid >> 6);
  int lane = tid & 63;
  if (seg >= S) return;
  int end = offs[seg];
  int cnt = hist[seg];
  int st = end - cnt;
  float ax = 0.f, ay = 0.f;
  int i = st;
  for (; i + 4 <= end; i += 4) {
    int s0 = sorted_src[i + 0];
    int s1 = sorted_src[i + 1];
    int s2 = sorted_src[i + 2];
    int s3 = sorted_src[i + 3];
    float2 v0 = *(const float2*)(x + (size_t)s0 * DH + lane * 2);
    float2 v1 = *(const float2*)(x + (size_t)s1 * DH + lane * 2);
    float2 v2 = *(const float2*)(x + (size_t)s2 * DH + lane * 2);
    float2 v3 = *(const float2*)(x + (size_t)s3 * DH + lane * 2);
    ax += (v0.x + v1.x) + (v2.x + v3.x);
    ay += (v0.y + v1.y) + (v2.y + v3.y);
  }
  for (; i < end; i++) {
    int s = sorted_src[i];
    float2 v = *(const float2*)(x + (size_t)s * DH + lane * 2);
    ax += v.x;
    ay += v.y;
  }
  float inv = 1.f / fmaxf((float)cnt, 1.f);
  float2 a = make_float2(ax * inv, ay * inv);
  *(float2*)(agg1 + (size_t)seg * DH + lane * 2) = a;
}

// ---------- layer 1 GEMM: C[N,128] = [agg1 | x] @ [W1;Wr1], BM=128 BN=128 BK=32, 8x8 tile ----------
__global__ __launch_bounds__(256) void k_gemm1(const float* __restrict__ agg1, const float* __restrict__ x,
                                               const float* __restrict__ W1, const float* __restrict__ Wr1,
                                               const float* __restrict__ b1, float* __restrict__ h, int N) {
  __shared__ float At[32 * 136];  // [kk][row], row-read b128 conflict-free (r0 in {0,8,16,24} per wave)
  __shared__ float Bs[32 * 132];  // [kk][col], col-read b128 conflict-free (proven r3)
  int tid = threadIdx.x;
  int n0 = blockIdx.x * 128;

  float acc[8][8];
  #pragma unroll
  for (int i = 0; i < 8; i++)
    #pragma unroll
    for (int j = 0; j < 8; j++) acc[i][j] = 0.f;

  int r0 = (tid >> 4) * 8;   // 8 contiguous output rows
  int c0 = (tid & 15) * 4;   // cols c0..c0+3, c0+64..c0+67

  int arow = tid >> 1;       // staging: 2 threads per A-row, 16 k each
  int gt   = tid & 1;
  int bcol = (tid & 31) * 4;
  int bk   = tid >> 5;       // 0..7, rows bk+8i

  float4 ra[4], rb[4];

  #define LOADA(kc)                                                                  \
    {                                                                                \
      const float* base_; size_t str_; int kb_;                                      \
      if ((kc) < 32) { base_ = agg1; str_ = 1024; kb_ = (kc) * 32; }                 \
      else           { base_ = x;    str_ = 128;  kb_ = ((kc) - 32) * 32; }          \
      int n_ = n0 + arow;                                                            \
      const float* p_ = base_ + (size_t)n_ * str_ + kb_ + gt * 16;                   \
      _Pragma("unroll")                                                              \
      for (int i_ = 0; i_ < 4; i_++)                                                 \
        ra[i_] = (n_ < N) ? *(const float4*)(p_ + 4 * i_) : make_float4(0,0,0,0);    \
    }
  #define LOADB(kc)                                                                  \
    {                                                                                \
      const float* base_; int kb_;                                                   \
      if ((kc) < 32) { base_ = W1;  kb_ = (kc) * 32; }                               \
      else           { base_ = Wr1; kb_ = ((kc) - 32) * 32; }                        \
      _Pragma("unroll")                                                              \
      for (int i_ = 0; i_ < 4; i_++)                                                 \
        rb[i_] = *(const float4*)(base_ + (size_t)(kb_ + bk + 8 * i_) * 128 + bcol); \
    }

  LOADA(0);
  LOADB(0);

  for (int kc = 0; kc < 36; kc++) {
    // At: transpose-write (2-way write aliasing only)
    #pragma unroll
    for (int i = 0; i < 4; i++) {
      int kk = gt * 16 + 4 * i;
      At[(kk + 0) * 136 + arow] = ra[i].x;
      At[(kk + 1) * 136 + arow] = ra[i].y;
      At[(kk + 2) * 136 + arow] = ra[i].z;
      At[(kk + 3) * 136 + arow] = ra[i].w;
    }
    #pragma unroll
    for (int i = 0; i < 4; i++)
      *(float4*)(Bs + (bk + 8 * i) * 132 + bcol) = rb[i];
    __syncthreads();

    if (kc + 1 < 36) {
      LOADA(kc + 1);
      LOADB(kc + 1);
    }

    #pragma unroll
    for (int kk = 0; kk < 32; kk++) {
      float4 a0 = *(const float4*)(At + kk * 136 + r0);
      float4 a1 = *(const float4*)(At + kk * 136 + r0 + 4);
      float4 b0 = *(const float4*)(Bs + kk * 132 + c0);
      float4 b1v = *(const float4*)(Bs + kk * 132 + c0 + 64);
      float av[8] = {a0.x, a0.y, a0.z, a0.w, a1.x, a1.y, a1.z, a1.w};
      float bv[8] = {b0.x, b0.y, b0.z, b0.w, b1v.x, b1v.y, b1v.z, b1v.w};
      #pragma unroll
      for (int i = 0; i < 8; i++)
        #pragma unroll
        for (int j = 0; j < 8; j++) acc[i][j] += av[i] * bv[j];
    }
    __syncthreads();
  }

  #pragma unroll
  for (int i = 0; i < 8; i++) {
    int n = n0 + r0 + i;
    if (n < N) {
      float4 o0, o1;
      o0.x = fmaxf(acc[i][0] + b1[c0 + 0], 0.f);
      o0.y = fmaxf(acc[i][1] + b1[c0 + 1], 0.f);
      o0.z = fmaxf(acc[i][2] + b1[c0 + 2], 0.f);
      o0.w = fmaxf(acc[i][3] + b1[c0 + 3], 0.f);
      o1.x = fmaxf(acc[i][4] + b1[c0 + 64], 0.f);
      o1.y = fmaxf(acc[i][5] + b1[c0 + 65], 0.f);
      o1.z = fmaxf(acc[i][6] + b1[c0 + 66], 0.f);
      o1.w = fmaxf(acc[i][7] + b1[c0 + 67], 0.f);
      *(float4*)(h + (size_t)n * DH + c0) = o0;
      *(float4*)(h + (size_t)n * DH + c0 + 64) = o1;
    }
  }
  #undef LOADA
  #undef LOADB
}

// ---------- layer-2 transform: t[n,0:18] = h[n] @ [W2_r(:,0:2)... | Wr2] ----------
__global__ __launch_bounds__(256) void k_l2trans(const float* __restrict__ h, const float* __restrict__ W2,
                                                 const float* __restrict__ Wr2, float* __restrict__ t, int N) {
  __shared__ float Wt[18 * 128];
  int tid = threadIdx.x;
  for (int i = tid; i < 2304; i += 256) {
    float v; int oc, d;
    if (i < 2048) { int r = i >> 8, rem = i & 255; d = rem >> 1; int c = rem & 1; oc = r * 2 + c; v = W2[i]; }
    else { int i2 = i - 2048; d = i2 >> 1; int c = i2 & 1; oc = 16 + c; v = Wr2[i2]; }
    Wt[oc * 128 + d] = v;
  }
  __syncthreads();
  int node = blockIdx.x * 4 + (tid >> 6);
  int lane = tid & 63;
  if (node >= N) return;
  float2 hv = *(const float2*)(h + (size_t)node * DH + lane * 2);
  #pragma unroll
  for (int oc = 0; oc < 18; oc++) {
    float2 w = *(const float2*)(Wt + oc * 128 + lane * 2);
    float p = hv.x * w.x + hv.y * w.y;
    p += __shfl_xor(p, 32); p += __shfl_xor(p, 16); p += __shfl_xor(p, 8);
    p += __shfl_xor(p, 4);  p += __shfl_xor(p, 2);  p += __shfl_xor(p, 1);
    if (lane == 0) t[(size_t)node * 18 + oc] = p;
  }
}

// ---------- output: gather tiny t values per segment ----------
__global__ __launch_bounds__(256) void k_out2(const int* __restrict__ offs, const int* __restrict__ hist,
                                              const int* __restrict__ sorted_src, const float* __restrict__ t,
                                              const float* __restrict__ b2, float* __restrict__ out, int N) {
  int n = blockIdx.x * 256 + threadIdx.x;
  if (n >= N) return;
  float o0 = t[(size_t)n * 18 + 16] + b2[0];
  float o1 = t[(size_t)n * 18 + 17] + b2[1];
  #pragma unroll
  for (int r = 0; r < NR; r++) {
    int seg = n * NR + r;
    int en = offs[seg], cc = hist[seg];
    float s0 = 0.f, s1 = 0.f;
    for (int i = en - cc; i < en; i++) {
      int s = sorted_src[i];
      s0 += t[(size_t)s * 18 + r * 2];
      s1 += t[(size_t)s * 18 + r * 2 + 1];
    }
    float inv = 1.f / fmaxf((float)cc, 1.f);
    o0 += s0 * inv;
    o1 += s1 * inv;
  }
  out[(size_t)n * 2 + 0] = o0;
  out[(size_t)n * 2 + 1] = o1;
}

extern "C" void kernel_launch(void* const* d_in, const int* in_sizes, int n_in,
                              void* d_out, int out_size, void* d_ws, size_t ws_size,
                              hipStream_t stream) {
  const float* x   = (const float*)d_in[0];
  const int*   ei  = (const int*)d_in[1];
  const int*   et  = (const int*)d_in[2];
  const float* W1  = (const float*)d_in[3];
  const float* Wr1 = (const float*)d_in[4];
  const float* b1  = (const float*)d_in[5];
  const float* W2  = (const float*)d_in[6];
  const float* Wr2 = (const float*)d_in[7];
  const float* b2  = (const float*)d_in[8];
  float* out = (float*)d_out;

  int E = in_sizes[1] / 2;
  int N = in_sizes[0] / DH;
  int S = N * NR;
  const int* src = ei;
  const int* dst = ei + E;

  int* hist       = (int*)d_ws;                  // S
  int* offs       = hist + S;                    // S
  int* blksum     = offs + S;                    // 1024
  int* blkoff     = blksum + 1024;               // 1024
  int* sorted_src = blkoff + 1024;               // E
  size_t int_elems = (size_t)S * 2 + 2048 + E;
  int_elems = (int_elems + 3) & ~(size_t)3;
  float* agg1 = (float*)(hist + int_elems);      // S*128
  float* h    = agg1 + (size_t)S * DH;           // N*128
  float* t    = h + (size_t)N * DH;              // N*18

  hipMemsetAsync(hist, 0, sizeof(int) * (size_t)S, stream);

  k_hist<<<(E + 255) / 256, 256, 0, stream>>>(dst, et, hist, E);

  int NB = (S + 1023) / 1024;
  k_scan_local<<<NB, 256, 0, stream>>>(hist, offs, blksum, S);
  k_scan_blk<<<1, 512, 0, stream>>>(blksum, blkoff, NB);
  k_scan_add<<<NB, 256, 0, stream>>>(offs, blkoff, S);

  k_scatter_idx<<<(E + 255) / 256, 256, 0, stream>>>(src, dst, et, offs, sorted_src, E);

  k_agg1<<<(S + 3) / 4, 256, 0, stream>>>(offs, hist, sorted_src, x, agg1, S);

  k_gemm1<<<(N + 127) / 128, 256, 0, stream>>>(agg1, x, W1, Wr1, b1, h, N);

  k_l2trans<<<(N + 3) / 4, 256, 0, stream>>>(h, W2, Wr2, t, N);

  k_out2<<<(N + 255) / 256, 256, 0, stream>>>(offs, hist, sorted_src, t, b2, out, N);
}

// Round 6
// 490.024 us; speedup vs baseline: 1.5032x; 1.1863x over previous
//
#include <hip/hip_runtime.h>
#include <hip/hip_bf16.h>

// RGCN 2-layer forward, f32 accuracy. CSR counting-sort; layer-1 GEMM via
// split-bf16 (hi+lo) 3-term MFMA (error ~2^-17 rel, f32-equivalent).
// L1: aggH/aggL[seg][128] = bf16-split mean x[src]; h = relu([agg|x] @ [W1;Wr1] + b1)
//     MFMA 16x16x32_bf16: C = Ah*Bh + Ah*Bl + Al*Bh, f32 accum.
// L2: t[n,0:18] = h[n] @ [W2_r(:,0:2).. | Wr2]; out = sum_r mean t[src,2r:2r+2] + t[n,16:18] + b2.

#define NR 8
#define DH 128

typedef short short8 __attribute__((ext_vector_type(8)));
typedef float f32x4 __attribute__((ext_vector_type(4)));

__device__ inline ushort f2bf(float v) {
  __hip_bfloat16 b = __float2bfloat16(v);
  return *reinterpret_cast<ushort*>(&b);
}
__device__ inline float bf2f(ushort u) {
  __hip_bfloat16 b;
  *reinterpret_cast<ushort*>(&b) = u;
  return __bfloat162float(b);
}
union U128 { uint4 u; short8 s; };

// ---------- counting sort ----------
__global__ __launch_bounds__(256) void k_hist(const int* __restrict__ dst, const int* __restrict__ et,
                                              int* __restrict__ hist, int E) {
  int e = blockIdx.x * 256 + threadIdx.x;
  if (e < E) atomicAdd(&hist[dst[e] * NR + et[e]], 1);
}

__global__ __launch_bounds__(256) void k_scan_local(const int* __restrict__ hist, int* __restrict__ offs,
                                                    int* __restrict__ blksum, int S) {
  __shared__ int tsum[256];
  int tid = threadIdx.x;
  int base = blockIdx.x * 1024 + tid * 4;
  int v[4], tot = 0;
  #pragma unroll
  for (int i = 0; i < 4; i++) { v[i] = (base + i < S) ? hist[base + i] : 0; tot += v[i]; }
  tsum[tid] = tot;
  __syncthreads();
  for (int off = 1; off < 256; off <<= 1) {
    int val = tsum[tid];
    int add = (tid >= off) ? tsum[tid - off] : 0;
    __syncthreads();
    tsum[tid] = val + add;
    __syncthreads();
  }
  int run = tsum[tid] - tot;
  #pragma unroll
  for (int i = 0; i < 4; i++) {
    if (base + i < S) offs[base + i] = run;
    run += v[i];
  }
  if (tid == 255) blksum[blockIdx.x] = tsum[255];
}

__global__ __launch_bounds__(512) void k_scan_blk(const int* __restrict__ blksum, int* __restrict__ blkoff, int NB) {
  __shared__ int s[512];
  int tid = threadIdx.x;
  int v = (tid < NB) ? blksum[tid] : 0;
  s[tid] = v;
  __syncthreads();
  for (int off = 1; off < 512; off <<= 1) {
    int val = s[tid];
    int add = (tid >= off) ? s[tid - off] : 0;
    __syncthreads();
    s[tid] = val + add;
    __syncthreads();
  }
  if (tid < NB) blkoff[tid] = s[tid] - v;
}

__global__ __launch_bounds__(256) void k_scan_add(int* __restrict__ offs, const int* __restrict__ blkoff, int S) {
  int tid = threadIdx.x;
  int base = blockIdx.x * 1024 + tid * 4;
  int add = blkoff[blockIdx.x];
  #pragma unroll
  for (int i = 0; i < 4; i++)
    if (base + i < S) offs[base + i] += add;
}

__global__ __launch_bounds__(256) void k_scatter_idx(const int* __restrict__ src, const int* __restrict__ dst,
                                                     const int* __restrict__ et, int* __restrict__ offs,
                                                     int* __restrict__ sorted_src, int E) {
  int e = blockIdx.x * 256 + threadIdx.x;
  if (e >= E) return;
  int seg = dst[e] * NR + et[e];
  int pos = atomicAdd(&offs[seg], 1);
  sorted_src[pos] = src[e];
}

// ---------- W split+transpose: Wt[col][k], k in [0,1152) ----------
__global__ __launch_bounds__(128) void k_wsplit(const float* __restrict__ W1, const float* __restrict__ Wr1,
                                                ushort* __restrict__ WtH, ushort* __restrict__ WtL) {
  int c = blockIdx.x;             // 0..127
  int k = blockIdx.y * 128 + threadIdx.x;  // 0..1151
  float v = (k < 1024) ? W1[(size_t)k * 128 + c] : Wr1[(size_t)(k - 1024) * 128 + c];
  ushort hi = f2bf(v);
  ushort lo = f2bf(v - bf2f(hi));
  WtH[(size_t)c * 1152 + k] = hi;
  WtL[(size_t)c * 1152 + k] = lo;
}

// ---------- layer 1 aggregate: one wave per segment, writes bf16 hi/lo planes ----------
__global__ __launch_bounds__(256) void k_agg1(const int* __restrict__ offs, const int* __restrict__ hist,
                                              const int* __restrict__ sorted_src, const float* __restrict__ x,
                                              ushort* __restrict__ aggH, ushort* __restrict__ aggL, int S) {
  int tid = threadIdx.x;
  int seg = blockIdx.x * 4 + (tid >> 6);
  int lane = tid & 63;
  if (seg >= S) return;
  int end = offs[seg];
  int cnt = hist[seg];
  int st = end - cnt;
  float ax = 0.f, ay = 0.f;
  int i = st;
  for (; i + 4 <= end; i += 4) {
    int s0 = sorted_src[i + 0];
    int s1 = sorted_src[i + 1];
    int s2 = sorted_src[i + 2];
    int s3 = sorted_src[i + 3];
    float2 v0 = *(const float2*)(x + (size_t)s0 * DH + lane * 2);
    float2 v1 = *(const float2*)(x + (size_t)s1 * DH + lane * 2);
    float2 v2 = *(const float2*)(x + (size_t)s2 * DH + lane * 2);
    float2 v3 = *(const float2*)(x + (size_t)s3 * DH + lane * 2);
    ax += (v0.x + v1.x) + (v2.x + v3.x);
    ay += (v0.y + v1.y) + (v2.y + v3.y);
  }
  for (; i < end; i++) {
    int s = sorted_src[i];
    float2 v = *(const float2*)(x + (size_t)s * DH + lane * 2);
    ax += v.x;
    ay += v.y;
  }
  float inv = 1.f / fmaxf((float)cnt, 1.f);
  ax *= inv;
  ay *= inv;
  ushort hx = f2bf(ax), hy = f2bf(ay);
  ushort lx = f2bf(ax - bf2f(hx)), ly = f2bf(ay - bf2f(hy));
  ushort2 hv; hv.x = hx; hv.y = hy;
  ushort2 lv; lv.x = lx; lv.y = ly;
  *(ushort2*)(aggH + (size_t)seg * DH + lane * 2) = hv;
  *(ushort2*)(aggL + (size_t)seg * DH + lane * 2) = lv;
}

// ---------- layer 1 MFMA GEMM: h[N,128] = relu([agg|x] @ [W1;Wr1] + b1) ----------
// 256 thr = 4 waves (2x2). Block tile 128x128, wave tile 64x64 (4x4 16x16 frags).
// A-frags from global (rows wave-private); B staged in LDS (block-shared).
// 3-term split: acc = Ah*Bh + Ah*Bl + Al*Bh (f32 accumulate).
__global__ __launch_bounds__(256) void k_gemm1_mfma(
    const ushort* __restrict__ aggH, const ushort* __restrict__ aggL,
    const float* __restrict__ xf,
    const ushort* __restrict__ WtH, const ushort* __restrict__ WtL,
    const float* __restrict__ b1, float* __restrict__ h, int N) {
  __shared__ ushort BsH[128 * 32];
  __shared__ ushort BsL[128 * 32];

  int tid = threadIdx.x;
  int w = tid >> 6, lane = tid & 63;
  int wr = w >> 1, wc = w & 1;
  int n0 = blockIdx.x * 128;

  int frow = lane & 15;
  int fk8 = (lane >> 4) * 8;

  // B staging: threads 0-127 hi plane, 128-255 lo plane; each stages one col's 32 k (64 B).
  int sp = tid >> 7;
  int sc = tid & 127;
  const ushort* Wt = sp ? WtL : WtH;
  ushort* Bss = (sp ? BsL : BsH) + sc * 32;
  const ushort* wsrc = Wt + (size_t)sc * 1152;

  f32x4 acc[4][4];
  #pragma unroll
  for (int i = 0; i < 4; i++)
    #pragma unroll
    for (int j = 0; j < 4; j++) acc[i][j] = (f32x4){0.f, 0.f, 0.f, 0.f};

  uint4 praw[4][2];
  uint4 rb[4];
  short8 aH[4], aL[4];

  int arow[4];
  #pragma unroll
  for (int ft = 0; ft < 4; ft++) {
    int r = n0 + wr * 64 + ft * 16 + frow;
    arow[ft] = (r < N) ? r : (N - 1);  // clamp: OOB rows compute garbage, never stored
  }

  #define LOADA(kc)                                                              \
    {                                                                            \
      if ((kc) < 32) {                                                           \
        _Pragma("unroll")                                                        \
        for (int ft = 0; ft < 4; ft++) {                                         \
          size_t base = (size_t)arow[ft] * 1024 + (kc) * 32 + fk8;               \
          praw[ft][0] = *(const uint4*)(aggH + base);                            \
          praw[ft][1] = *(const uint4*)(aggL + base);                            \
        }                                                                        \
      } else {                                                                   \
        _Pragma("unroll")                                                        \
        for (int ft = 0; ft < 4; ft++) {                                         \
          const uint4* xp = (const uint4*)(xf + (size_t)arow[ft] * 128 +         \
                                           ((kc) - 32) * 32 + fk8);              \
          praw[ft][0] = xp[0];                                                   \
          praw[ft][1] = xp[1];                                                   \
        }                                                                        \
      }                                                                          \
    }
  #define LOADB(kc)                                                              \
    {                                                                            \
      const uint4* ws_ = (const uint4*)(wsrc + (kc) * 32);                       \
      rb[0] = ws_[0]; rb[1] = ws_[1]; rb[2] = ws_[2]; rb[3] = ws_[3];            \
    }

  LOADA(0);
  LOADB(0);

  for (int kc = 0; kc < 36; kc++) {
    // Bs <- prefetched W regs
    {
      uint4* d = (uint4*)Bss;
      d[0] = rb[0]; d[1] = rb[1]; d[2] = rb[2]; d[3] = rb[3];
    }
    __syncthreads();

    // decode current A frags from raw prefetch
    if (kc < 32) {
      #pragma unroll
      for (int ft = 0; ft < 4; ft++) {
        U128 uh, ul;
        uh.u = praw[ft][0];
        ul.u = praw[ft][1];
        aH[ft] = uh.s;
        aL[ft] = ul.s;
      }
    } else {
      #pragma unroll
      for (int ft = 0; ft < 4; ft++) {
        union { uint4 u[2]; float f[8]; } xx;
        xx.u[0] = praw[ft][0];
        xx.u[1] = praw[ft][1];
        short8 th, tl;
        #pragma unroll
        for (int j = 0; j < 8; j++) {
          ushort hb = f2bf(xx.f[j]);
          th[j] = (short)hb;
          tl[j] = (short)f2bf(xx.f[j] - bf2f(hb));
        }
        aH[ft] = th;
        aL[ft] = tl;
      }
    }

    if (kc < 35) {
      LOADA(kc + 1);
      LOADB(kc + 1);
    }

    #pragma unroll
    for (int ct = 0; ct < 4; ct++) {
      int gcol = wc * 64 + ct * 16 + frow;
      const short8 bH = *(const short8*)(BsH + gcol * 32 + fk8);
      const short8 bL = *(const short8*)(BsL + gcol * 32 + fk8);
      #pragma unroll
      for (int ft = 0; ft < 4; ft++) {
        acc[ft][ct] = __builtin_amdgcn_mfma_f32_16x16x32_bf16(aH[ft], bH, acc[ft][ct], 0, 0, 0);
        acc[ft][ct] = __builtin_amdgcn_mfma_f32_16x16x32_bf16(aH[ft], bL, acc[ft][ct], 0, 0, 0);
        acc[ft][ct] = __builtin_amdgcn_mfma_f32_16x16x32_bf16(aL[ft], bH, acc[ft][ct], 0, 0, 0);
      }
    }
    __syncthreads();
  }
  #undef LOADA
  #undef LOADB

  // epilogue: D layout col=lane&15, row=(lane>>4)*4+q
  float bias[4];
  #pragma unroll
  for (int ct = 0; ct < 4; ct++) bias[ct] = b1[wc * 64 + ct * 16 + frow];

  int rbase = n0 + wr * 64 + (lane >> 4) * 4;
  #pragma unroll
  for (int ft = 0; ft < 4; ft++) {
    #pragma unroll
    for (int ct = 0; ct < 4; ct++) {
      int C = wc * 64 + ct * 16 + frow;
      #pragma unroll
      for (int q = 0; q < 4; q++) {
        int R = rbase + ft * 16 + q;
        if (R < N) h[(size_t)R * 128 + C] = fmaxf(acc[ft][ct][q] + bias[ct], 0.f);
      }
    }
  }
}

// ---------- layer-2 transform: t[n,0:18] = h[n] @ [W2_r(:,0:2)... | Wr2] ----------
__global__ __launch_bounds__(256) void k_l2trans(const float* __restrict__ h, const float* __restrict__ W2,
                                                 const float* __restrict__ Wr2, float* __restrict__ t, int N) {
  __shared__ float Wt[18 * 128];
  int tid = threadIdx.x;
  for (int i = tid; i < 2304; i += 256) {
    float v; int oc, d;
    if (i < 2048) { int r = i >> 8, rem = i & 255; d = rem >> 1; int c = rem & 1; oc = r * 2 + c; v = W2[i]; }
    else { int i2 = i - 2048; d = i2 >> 1; int c = i2 & 1; oc = 16 + c; v = Wr2[i2]; }
    Wt[oc * 128 + d] = v;
  }
  __syncthreads();
  int node = blockIdx.x * 4 + (tid >> 6);
  int lane = tid & 63;
  if (node >= N) return;
  float2 hv = *(const float2*)(h + (size_t)node * DH + lane * 2);
  #pragma unroll
  for (int oc = 0; oc < 18; oc++) {
    float2 w = *(const float2*)(Wt + oc * 128 + lane * 2);
    float p = hv.x * w.x + hv.y * w.y;
    p += __shfl_xor(p, 32); p += __shfl_xor(p, 16); p += __shfl_xor(p, 8);
    p += __shfl_xor(p, 4);  p += __shfl_xor(p, 2);  p += __shfl_xor(p, 1);
    if (lane == 0) t[(size_t)node * 18 + oc] = p;
  }
}

// ---------- output: gather tiny t values per segment ----------
__global__ __launch_bounds__(256) void k_out2(const int* __restrict__ offs, const int* __restrict__ hist,
                                              const int* __restrict__ sorted_src, const float* __restrict__ t,
                                              const float* __restrict__ b2, float* __restrict__ out, int N) {
  int n = blockIdx.x * 256 + threadIdx.x;
  if (n >= N) return;
  float o0 = t[(size_t)n * 18 + 16] + b2[0];
  float o1 = t[(size_t)n * 18 + 17] + b2[1];
  #pragma unroll
  for (int r = 0; r < NR; r++) {
    int seg = n * NR + r;
    int en = offs[seg], cc = hist[seg];
    float s0 = 0.f, s1 = 0.f;
    for (int i = en - cc; i < en; i++) {
      int s = sorted_src[i];
      s0 += t[(size_t)s * 18 + r * 2];
      s1 += t[(size_t)s * 18 + r * 2 + 1];
    }
    float inv = 1.f / fmaxf((float)cc, 1.f);
    o0 += s0 * inv;
    o1 += s1 * inv;
  }
  out[(size_t)n * 2 + 0] = o0;
  out[(size_t)n * 2 + 1] = o1;
}

extern "C" void kernel_launch(void* const* d_in, const int* in_sizes, int n_in,
                              void* d_out, int out_size, void* d_ws, size_t ws_size,
                              hipStream_t stream) {
  const float* x   = (const float*)d_in[0];
  const int*   ei  = (const int*)d_in[1];
  const int*   et  = (const int*)d_in[2];
  const float* W1  = (const float*)d_in[3];
  const float* Wr1 = (const float*)d_in[4];
  const float* b1  = (const float*)d_in[5];
  const float* W2  = (const float*)d_in[6];
  const float* Wr2 = (const float*)d_in[7];
  const float* b2  = (const float*)d_in[8];
  float* out = (float*)d_out;

  int E = in_sizes[1] / 2;
  int N = in_sizes[0] / DH;
  int S = N * NR;
  const int* src = ei;
  const int* dst = ei + E;

  // ws layout: ints | aggH aggL (bf16 planes) | WtH WtL | h | t
  int* hist       = (int*)d_ws;                  // S
  int* offs       = hist + S;                    // S
  int* blksum     = offs + S;                    // 1024
  int* blkoff     = blksum + 1024;               // 1024
  int* sorted_src = blkoff + 1024;               // E
  size_t int_elems = (size_t)S * 2 + 2048 + E;
  int_elems = (int_elems + 3) & ~(size_t)3;      // 16B align
  ushort* aggH = (ushort*)(hist + int_elems);    // S*128
  ushort* aggL = aggH + (size_t)S * DH;          // S*128
  ushort* WtH  = aggL + (size_t)S * DH;          // 128*1152
  ushort* WtL  = WtH + 128 * 1152;               // 128*1152
  size_t ush_elems = (size_t)S * DH * 2 + 2 * 128 * 1152;  // even -> float aligned
  float* h = (float*)(aggH + ush_elems);         // N*128
  float* t = h + (size_t)N * DH;                 // N*18

  hipMemsetAsync(hist, 0, sizeof(int) * (size_t)S, stream);

  k_hist<<<(E + 255) / 256, 256, 0, stream>>>(dst, et, hist, E);

  int NB = (S + 1023) / 1024;
  k_scan_local<<<NB, 256, 0, stream>>>(hist, offs, blksum, S);
  k_scan_blk<<<1, 512, 0, stream>>>(blksum, blkoff, NB);
  k_scan_add<<<NB, 256, 0, stream>>>(offs, blkoff, S);

  k_scatter_idx<<<(E + 255) / 256, 256, 0, stream>>>(src, dst, et, offs, sorted_src, E);

  k_wsplit<<<dim3(128, 9), 128, 0, stream>>>(W1, Wr1, WtH, WtL);

  k_agg1<<<(S + 3) / 4, 256, 0, stream>>>(offs, hist, sorted_src, x, aggH, aggL, S);

  k_gemm1_mfma<<<(N + 127) / 128, 256, 0, stream>>>(aggH, aggL, x, WtH, WtL, b1, h, N);

  k_l2trans<<<(N + 3) / 4, 256, 0, stream>>>(h, W2, Wr2, t, N);

  k_out2<<<(N + 255) / 256, 256, 0, stream>>>(offs, hist, sorted_src, t, b2, out, N);
}